// Round 1
// baseline (671.785 us; speedup 1.0000x reference)
//
#include <hip/hip_runtime.h>
#include <hip/hip_bf16.h>

typedef unsigned int  u32;
typedef unsigned short u16;
typedef __attribute__((ext_vector_type(8)))  short short8;
typedef __attribute__((ext_vector_type(16))) float f32x16;

#define B_ 64
#define N_ 2048
#define I_ 16
#define J_ 32
#define K_ 32
#define CH_  32        // n-chunks for accum (block covers 64 n, wave 16)
#define WTOT ((size_t)J_*N_*K_*I_)   // 33,554,432 W elements

__device__ __forceinline__ float bf2f(u16 u){ return __uint_as_float(((u32)u)<<16); }
__device__ __forceinline__ short f2bf(float f){
  __hip_bfloat16 h = __float2bfloat16(f);
  short s; __builtin_memcpy(&s, &h, 2); return s;
}

// ---- dtype sniffer + zero finisher counters (1 block) -------------------
__global__ __launch_bounds__(256) void detect(const u16* __restrict__ X,
                                              const u16* __restrict__ W,
                                              int* __restrict__ flags,
                                              int* __restrict__ cnt)
{
  if (threadIdx.x < 96) cnt[threadIdx.x] = 0;
  __shared__ int sx, sw;
  if (threadIdx.x == 0){ sx = 0; sw = 0; }
  __syncthreads();
  int bx = 0, bw = 0;
  for (int i = threadIdx.x; i < 8192; i += 256){
    int ex = (X[2*i] >> 7) & 0xFF;
    int ew = (W[2*i] >> 7) & 0xFF;
    if (ex >= 0x90) bx = 1;
    if (ew >= 0x90) bw = 1;
  }
  if (bx) atomicOr(&sx, 1);
  if (bw) atomicOr(&sw, 1);
  __syncthreads();
  if (threadIdx.x == 0){ flags[0] = sx; flags[1] = sw; }
}

// ---- merged pack: blocks [0,8192) pack W, [8192,8704) pack X ------------
// X_p[n][lane][t*8+q] = bf16( x[b = t*32+(lane&31)][n][i = (lane>>5)*8+q] )
__global__ __launch_bounds__(256) void pack_xw(const void* __restrict__ Xv,
                                               const void* __restrict__ Wv,
                                               const int* __restrict__ flags,
                                               u16* __restrict__ X_p,
                                               u16* __restrict__ W_p)
{
  if (blockIdx.x < 8192){
    const size_t base = ((size_t)blockIdx.x*256 + threadIdx.x)*16;
    if (flags[1]){
      const float4* src = (const float4*)((const float*)Wv + base);
      float4 v0=src[0], v1=src[1], v2=src[2], v3=src[3];
      short8 a, b;
      a[0]=f2bf(v0.x); a[1]=f2bf(v0.y); a[2]=f2bf(v0.z); a[3]=f2bf(v0.w);
      a[4]=f2bf(v1.x); a[5]=f2bf(v1.y); a[6]=f2bf(v1.z); a[7]=f2bf(v1.w);
      b[0]=f2bf(v2.x); b[1]=f2bf(v2.y); b[2]=f2bf(v2.z); b[3]=f2bf(v2.w);
      b[4]=f2bf(v3.x); b[5]=f2bf(v3.y); b[6]=f2bf(v3.z); b[7]=f2bf(v3.w);
      *(short8*)(W_p + base)     = a;
      *(short8*)(W_p + base + 8) = b;
    } else {
      const short8* src = (const short8*)((const u16*)Wv + base);
      *(short8*)(W_p + base)     = src[0];
      *(short8*)(W_p + base + 8) = src[1];
    }
  } else {
    const int bid = blockIdx.x - 8192;
    const int l = threadIdx.x & 63, w = threadIdx.x >> 6;
    const int n = bid*4 + w;
    const bool xf32 = flags[0] != 0;
    const int ih = (l>>5)*8;
    u16 out[16];
    #pragma unroll
    for (int t=0;t<2;++t){
      const int b = t*32 + (l&31);
      if (xf32){
        const float4* xp = (const float4*)((const float*)Xv + ((size_t)b*N_ + n)*I_ + ih);
        float4 v0 = xp[0], v1 = xp[1];
        out[t*8+0]=(u16)f2bf(v0.x); out[t*8+1]=(u16)f2bf(v0.y);
        out[t*8+2]=(u16)f2bf(v0.z); out[t*8+3]=(u16)f2bf(v0.w);
        out[t*8+4]=(u16)f2bf(v1.x); out[t*8+5]=(u16)f2bf(v1.y);
        out[t*8+6]=(u16)f2bf(v1.z); out[t*8+7]=(u16)f2bf(v1.w);
      } else {
        const u16* xp = (const u16*)Xv + ((size_t)b*N_ + n)*I_ + ih;
        #pragma unroll
        for (int q=0;q<8;++q) out[t*8+q] = xp[q];
      }
    }
    u16* dst = X_p + (size_t)n*1024 + l*16;
    short8 s0, s1;
    #pragma unroll
    for (int q=0;q<8;++q){ s0[q]=(short)out[q]; s1[q]=(short)out[8+q]; }
    *(short8*)dst = s0;
    *(short8*)(dst+8) = s1;
  }
}

// ---- accum + last-block-per-j finisher (reduce over chunks + squash) ----
// R: 0 = uniform c (1/32 folded in squash), 1 = weighted c = e * invS
// SQ: 0 = write o_t (iter0), 1 = o_t += (iter1), 2 = write d_out (final)
template<int R, int SQ>
__global__ __launch_bounds__(256) void accum_fin(
    const u16* __restrict__ X_p, const u16* __restrict__ W_p,
    const float* __restrict__ c_buf, const float* __restrict__ sumb,
    float* __restrict__ part, int* __restrict__ cnt,
    float* __restrict__ o_t, const int* __restrict__ flags,
    void* __restrict__ d_out)
{
  __shared__ float red[4][2048];
  __shared__ int lastf;
  const int l  = threadIdx.x & 63;
  const int w  = threadIdx.x >> 6;
  const int j  = blockIdx.y;
  const int ch = blockIdx.x;
  const int n0 = ch*64 + w*16;
  const int kc = l & 31;
  const int ih = (l >> 5) * 8;

  f32x16 C0, C1;
  #pragma unroll
  for (int r=0;r<16;++r){ C0[r]=0.f; C1[r]=0.f; }

  #pragma unroll 4
  for (int t=0;t<16;++t){
    const int n = n0 + t;
    const u16* xp = X_p + (size_t)n*1024 + l*16;
    short8 xa0 = *(const short8*)xp;
    short8 xa1 = *(const short8*)(xp+8);
    short8 a0, a1;
    if constexpr (R==0){ a0 = xa0; a1 = xa1; }
    else {
      const float iS0 = sumb[(size_t)n*64 + kc];
      const float iS1 = sumb[(size_t)n*64 + 32 + kc];
      const float c0 = iS0 * c_buf[((size_t)n*J_ + j)*64 + kc];
      const float c1 = iS1 * c_buf[((size_t)n*J_ + j)*64 + 32 + kc];
      #pragma unroll
      for (int q=0;q<8;++q){
        a0[q] = f2bf(c0 * bf2f((u16)xa0[q]));
        a1[q] = f2bf(c1 * bf2f((u16)xa1[q]));
      }
    }
    short8 bfr = *(const short8*)(W_p + ((size_t)j*N_ + n)*512 + kc*16 + ih);
    C0 = __builtin_amdgcn_mfma_f32_32x32x16_bf16(a0, bfr, C0, 0,0,0);
    C1 = __builtin_amdgcn_mfma_f32_32x32x16_bf16(a1, bfr, C1, 0,0,0);
  }

  #pragma unroll
  for (int r=0;r<16;++r){
    red[w][r*64 + l]      = C0[r];
    red[w][(16+r)*64 + l] = C1[r];
  }
  __syncthreads();

  float* dst = part + ((size_t)ch*J_ + j)*2048;
  for (int p = threadIdx.x; p < 2048; p += 256)
    dst[p] = red[0][p] + red[1][p] + red[2][p] + red[3][p];

  // ticket: writes -> per-thread device fence -> barrier -> atomic
  __threadfence();
  __syncthreads();
  if (threadIdx.x == 0) lastf = (atomicAdd(cnt + j, 1) == CH_-1);
  __syncthreads();
  if (!lastf) return;
  __threadfence();   // acquire side

  // reduce partials over chunks into red[0][k][b]
  for (int p = threadIdx.x; p < 2048; p += 256){
    float sum = 0.f;
    #pragma unroll 4
    for (int c2=0; c2<CH_; ++c2)
      sum += part[((size_t)c2*J_ + j)*2048 + p];
    const int r  = p >> 6, ll = p & 63;
    const int kk = ll & 31, h = ll >> 5;
    const int rr = r & 15, tile = r >> 4;
    const int b  = tile*32 + (rr&3) + 8*(rr>>2) + 4*h;
    red[0][kk*64 + b] = sum;
  }
  __syncthreads();

  if (threadIdx.x < 64){
    const int b = threadIdx.x;
    float sq = 0.f;
    #pragma unroll
    for (int k=0;k<K_;++k){
      float v = red[0][k*64 + b];
      if constexpr (SQ==0) v *= (1.0f/32.0f);
      sq += v*v;
    }
    const float scale = sq/(1.f+sq)/sqrtf(sq+1e-7f);
    if constexpr (SQ==0){
      #pragma unroll
      for (int k=0;k<K_;++k)
        o_t[((size_t)j*K_ + k)*64 + b] = scale * red[0][k*64+b] * (1.0f/32.0f);
    } else if constexpr (SQ==1){
      #pragma unroll
      for (int k=0;k<K_;++k)
        o_t[((size_t)j*K_ + k)*64 + b] += scale * red[0][k*64+b];
    } else {
      const bool f32o = (flags[0]!=0) && (flags[1]!=0);
      if (f32o){
        float* po = (float*)d_out;
        #pragma unroll
        for (int k=0;k<K_;++k)
          po[(size_t)b*(J_*K_) + j*K_ + k] = scale * red[0][k*64+b];
      } else {
        __hip_bfloat16* po = (__hip_bfloat16*)d_out;
        #pragma unroll
        for (int k=0;k<K_;++k)
          po[(size_t)b*(J_*K_) + j*K_ + k] = __float2bfloat16(scale * red[0][k*64+b]);
      }
    }
  }
}

// ---- logits: LDS-free via operand swap; writes exp(logit) ---------------
// c_buf[n][j][b] = exp( sum_k o[b,j,k]*u_hat[b,j,n,k] )   (bounded, no max needed)
__global__ __launch_bounds__(256) void logits_kernel(
    const u16* __restrict__ X_p, const u16* __restrict__ W_p,
    const float* __restrict__ o_t, float* __restrict__ c_buf)
{
  const int l  = threadIdx.x & 63;
  const int w  = threadIdx.x >> 6;
  const int j  = blockIdx.y;
  const int n0 = blockIdx.x*32 + w*8;
  const int kc = l & 31;          // = column index = b (mod 32)
  const int h  = l >> 5;
  const int ih = h*8;

  float o_r0[16], o_r1[16];
  #pragma unroll
  for (int r=0;r<16;++r){
    const int k = (r&3) + 8*(r>>2) + 4*h;
    o_r0[r] = o_t[((size_t)j*K_ + k)*64 + kc];
    o_r1[r] = o_t[((size_t)j*K_ + k)*64 + 32 + kc];
  }

  #pragma unroll 2
  for (int t=0;t<8;++t){
    const int n = n0 + t;
    const u16* xp = X_p + (size_t)n*1024 + l*16;
    short8 xa0 = *(const short8*)xp;
    short8 xa1 = *(const short8*)(xp+8);
    short8 wfr = *(const short8*)(W_p + ((size_t)j*N_ + n)*512 + kc*16 + ih);
    f32x16 C0, C1;
    #pragma unroll
    for (int r=0;r<16;++r){ C0[r]=0.f; C1[r]=0.f; }
    C0 = __builtin_amdgcn_mfma_f32_32x32x16_bf16(wfr, xa0, C0, 0,0,0);
    C1 = __builtin_amdgcn_mfma_f32_32x32x16_bf16(wfr, xa1, C1, 0,0,0);
    float d0 = 0.f, d1 = 0.f;
    #pragma unroll
    for (int r=0;r<16;++r){ d0 += C0[r]*o_r0[r]; d1 += C1[r]*o_r1[r]; }
    d0 += __shfl_xor(d0, 32, 64);   // merge the two k-halves (same b)
    d1 += __shfl_xor(d1, 32, 64);
    const float val = (l >= 32) ? d1 : d0;   // lane l owns b=l
    c_buf[((size_t)n*J_ + j)*64 + l] = __expf(val);
  }
}

// ---- rowsum over j -> invS[n][b] (replaces normalize pass) --------------
__global__ __launch_bounds__(256) void rowsum(const float* __restrict__ c_buf,
                                              float* __restrict__ sumb)
{
  const int l = threadIdx.x & 63, w = threadIdx.x >> 6;
  const int n = blockIdx.x*4 + w;
  const float* p = c_buf + (size_t)n*J_*64 + l;
  float s = 0.f;
  #pragma unroll
  for (int jj=0;jj<J_;++jj) s += p[jj*64];
  sumb[(size_t)n*64 + l] = 1.0f/s;
}

extern "C" void kernel_launch(void* const* d_in, const int* in_sizes, int n_in,
                              void* d_out, int out_size, void* d_ws, size_t ws_size,
                              hipStream_t stream)
{
  const void* X  = d_in[0];   // [B][N][I]     (dtype sniffed)
  const void* Wm = d_in[1];   // [J][N][K][I]  (dtype sniffed)

  float* ws    = (float*)d_ws;
  float* o_t   = ws;                                  // 65536 f32, [j][k][b]
  int*   flags = (int*)(ws + 65536);                  // 2 ints
  int*   cnt   = flags + 16;                          // 96 ints (3 x 32)
  u16*   X_p   = (u16*)(ws + 65536 + 128);            // 2048*1024 u16 (4 MB)
  u16*   W_p   = X_p + (size_t)N_*1024;               // 33.5M u16 (64 MiB)
  float* c_buf = (float*)(W_p + WTOT);                // 2048*32*64 f32 (16 MiB)
  float* sumb  = c_buf + (size_t)N_*J_*64;            // 2048*64 f32 (512 KB)
  float* part  = sumb + (size_t)N_*64;                // CH_*32*2048 f32 (8 MiB)
  // total ~93 MiB of the 512 MiB workspace

  const dim3 blk(256);
  const dim3 g_ac(CH_, J_);    // accum: 1024 blocks
  const dim3 g_lg(64,  J_);    // logits: 2048 blocks

  detect<<<1, blk, 0, stream>>>((const u16*)X, (const u16*)Wm, flags, cnt);
  pack_xw<<<8192 + N_/4, blk, 0, stream>>>(X, Wm, flags, X_p, W_p);

  // iter 0: uniform c (1/32 folded into finisher squash)
  accum_fin<0,0><<<g_ac, blk, 0, stream>>>(X_p, W_p, nullptr, nullptr, part, cnt, o_t, flags, nullptr);

  // iter 1
  logits_kernel<<<g_lg, blk, 0, stream>>>(X_p, W_p, o_t, c_buf);
  rowsum<<<N_/4, blk, 0, stream>>>(c_buf, sumb);
  accum_fin<1,1><<<g_ac, blk, 0, stream>>>(X_p, W_p, c_buf, sumb, part, cnt+32, o_t, flags, nullptr);

  // iter 2
  logits_kernel<<<g_lg, blk, 0, stream>>>(X_p, W_p, o_t, c_buf);
  rowsum<<<N_/4, blk, 0, stream>>>(c_buf, sumb);
  accum_fin<1,2><<<g_ac, blk, 0, stream>>>(X_p, W_p, c_buf, sumb, part, cnt+64, o_t, flags, d_out);
}

// Round 2
// 381.305 us; speedup vs baseline: 1.7618x; 1.7618x over previous
//
#include <hip/hip_runtime.h>
#include <hip/hip_bf16.h>

typedef unsigned int  u32;
typedef unsigned short u16;
typedef __attribute__((ext_vector_type(8)))  short short8;
typedef __attribute__((ext_vector_type(16))) float f32x16;

#define B_ 64
#define N_ 2048
#define I_ 16
#define J_ 32
#define K_ 32
#define CH_  32        // n-chunks for accum (block covers 64 n, wave 16)
#define WTOT ((size_t)J_*N_*K_*I_)   // 33,554,432 W elements

__device__ __forceinline__ float bf2f(u16 u){ return __uint_as_float(((u32)u)<<16); }
__device__ __forceinline__ short f2bf(float f){
  __hip_bfloat16 h = __float2bfloat16(f);
  short s; __builtin_memcpy(&s, &h, 2); return s;
}

// ---- dtype sniffer (1 block) --------------------------------------------
__global__ __launch_bounds__(256) void detect(const u16* __restrict__ X,
                                              const u16* __restrict__ W,
                                              int* __restrict__ flags)
{
  __shared__ int sx, sw;
  if (threadIdx.x == 0){ sx = 0; sw = 0; }
  __syncthreads();
  int bx = 0, bw = 0;
  for (int i = threadIdx.x; i < 8192; i += 256){
    int ex = (X[2*i] >> 7) & 0xFF;
    int ew = (W[2*i] >> 7) & 0xFF;
    if (ex >= 0x90) bx = 1;
    if (ew >= 0x90) bw = 1;
  }
  if (bx) atomicOr(&sx, 1);
  if (bw) atomicOr(&sw, 1);
  __syncthreads();
  if (threadIdx.x == 0){ flags[0] = sx; flags[1] = sw; }
}

// ---- merged pack: blocks [0,8192) pack W, [8192,8704) pack X ------------
// X_p[n][lane][t*8+q] = bf16( x[b = t*32+(lane&31)][n][i = (lane>>5)*8+q] )
__global__ __launch_bounds__(256) void pack_xw(const void* __restrict__ Xv,
                                               const void* __restrict__ Wv,
                                               const int* __restrict__ flags,
                                               u16* __restrict__ X_p,
                                               u16* __restrict__ W_p)
{
  if (blockIdx.x < 8192){
    const size_t base = ((size_t)blockIdx.x*256 + threadIdx.x)*16;
    if (flags[1]){
      const float4* src = (const float4*)((const float*)Wv + base);
      float4 v0=src[0], v1=src[1], v2=src[2], v3=src[3];
      short8 a, b;
      a[0]=f2bf(v0.x); a[1]=f2bf(v0.y); a[2]=f2bf(v0.z); a[3]=f2bf(v0.w);
      a[4]=f2bf(v1.x); a[5]=f2bf(v1.y); a[6]=f2bf(v1.z); a[7]=f2bf(v1.w);
      b[0]=f2bf(v2.x); b[1]=f2bf(v2.y); b[2]=f2bf(v2.z); b[3]=f2bf(v2.w);
      b[4]=f2bf(v3.x); b[5]=f2bf(v3.y); b[6]=f2bf(v3.z); b[7]=f2bf(v3.w);
      *(short8*)(W_p + base)     = a;
      *(short8*)(W_p + base + 8) = b;
    } else {
      const short8* src = (const short8*)((const u16*)Wv + base);
      *(short8*)(W_p + base)     = src[0];
      *(short8*)(W_p + base + 8) = src[1];
    }
  } else {
    const int bid = blockIdx.x - 8192;
    const int l = threadIdx.x & 63, w = threadIdx.x >> 6;
    const int n = bid*4 + w;
    const bool xf32 = flags[0] != 0;
    const int ih = (l>>5)*8;
    u16 out[16];
    #pragma unroll
    for (int t=0;t<2;++t){
      const int b = t*32 + (l&31);
      if (xf32){
        const float4* xp = (const float4*)((const float*)Xv + ((size_t)b*N_ + n)*I_ + ih);
        float4 v0 = xp[0], v1 = xp[1];
        out[t*8+0]=(u16)f2bf(v0.x); out[t*8+1]=(u16)f2bf(v0.y);
        out[t*8+2]=(u16)f2bf(v0.z); out[t*8+3]=(u16)f2bf(v0.w);
        out[t*8+4]=(u16)f2bf(v1.x); out[t*8+5]=(u16)f2bf(v1.y);
        out[t*8+6]=(u16)f2bf(v1.z); out[t*8+7]=(u16)f2bf(v1.w);
      } else {
        const u16* xp = (const u16*)Xv + ((size_t)b*N_ + n)*I_ + ih;
        #pragma unroll
        for (int q=0;q<8;++q) out[t*8+q] = xp[q];
      }
    }
    u16* dst = X_p + (size_t)n*1024 + l*16;
    short8 s0, s1;
    #pragma unroll
    for (int q=0;q<8;++q){ s0[q]=(short)out[q]; s1[q]=(short)out[8+q]; }
    *(short8*)dst = s0;
    *(short8*)(dst+8) = s1;
  }
}

// ---- accum: per-(chunk,j) partial of s via MFMA (A=X, B=W), no atomics --
// R: 0 = uniform c (1/32 folded in squash), 1 = weighted c = e * invS
template<int R>
__global__ __launch_bounds__(256) void accum_kernel(
    const u16* __restrict__ X_p, const u16* __restrict__ W_p,
    const float* __restrict__ c_buf, const float* __restrict__ sumb,
    float* __restrict__ part)
{
  __shared__ float red[4][2048];
  const int l  = threadIdx.x & 63;
  const int w  = threadIdx.x >> 6;
  const int j  = blockIdx.y;
  const int ch = blockIdx.x;
  const int n0 = ch*64 + w*16;
  const int kc = l & 31;
  const int ih = (l >> 5) * 8;

  f32x16 C0, C1;
  #pragma unroll
  for (int r=0;r<16;++r){ C0[r]=0.f; C1[r]=0.f; }

  #pragma unroll 4
  for (int t=0;t<16;++t){
    const int n = n0 + t;
    const u16* xp = X_p + (size_t)n*1024 + l*16;
    short8 xa0 = *(const short8*)xp;
    short8 xa1 = *(const short8*)(xp+8);
    short8 a0, a1;
    if constexpr (R==0){ a0 = xa0; a1 = xa1; }
    else {
      const float iS0 = sumb[(size_t)n*64 + kc];
      const float iS1 = sumb[(size_t)n*64 + 32 + kc];
      const float c0 = iS0 * c_buf[((size_t)n*J_ + j)*64 + kc];
      const float c1 = iS1 * c_buf[((size_t)n*J_ + j)*64 + 32 + kc];
      #pragma unroll
      for (int q=0;q<8;++q){
        a0[q] = f2bf(c0 * bf2f((u16)xa0[q]));
        a1[q] = f2bf(c1 * bf2f((u16)xa1[q]));
      }
    }
    short8 bfr = *(const short8*)(W_p + ((size_t)j*N_ + n)*512 + kc*16 + ih);
    C0 = __builtin_amdgcn_mfma_f32_32x32x16_bf16(a0, bfr, C0, 0,0,0);
    C1 = __builtin_amdgcn_mfma_f32_32x32x16_bf16(a1, bfr, C1, 0,0,0);
  }

  #pragma unroll
  for (int r=0;r<16;++r){
    red[w][r*64 + l]      = C0[r];
    red[w][(16+r)*64 + l] = C1[r];
  }
  __syncthreads();

  float* dst = part + ((size_t)ch*J_ + j)*2048;
  #pragma unroll
  for (int p = threadIdx.x; p < 2048; p += 256)
    dst[p] = red[0][p] + red[1][p] + red[2][p] + red[3][p];
}

// ---- reduce partials over chunks + squash epilogue (no fences needed) ---
// SQ: 0 = write o_t (iter0, c=1/32), 1 = o_t += (iter1), 2 = write d_out
template<int SQ>
__global__ __launch_bounds__(256) void reduce_squash(
    const float* __restrict__ part, float* __restrict__ o_t,
    const int* __restrict__ flags, void* __restrict__ d_out)
{
  __shared__ float sacc[2048];
  const int j = blockIdx.x;
  for (int p = threadIdx.x; p < 2048; p += 256){
    float sum = 0.f;
    #pragma unroll 4
    for (int ch=0; ch<CH_; ++ch)
      sum += part[((size_t)ch*J_ + j)*2048 + p];
    const int r  = p >> 6, l = p & 63;
    const int kc = l & 31, h = l >> 5;
    const int rr = r & 15, tile = r >> 4;
    const int b  = tile*32 + (rr&3) + 8*(rr>>2) + 4*h;
    sacc[kc*64 + b] = sum;
  }
  __syncthreads();

  if (threadIdx.x < 64){
    const int b = threadIdx.x;
    float sq = 0.f;
    #pragma unroll
    for (int k=0;k<K_;++k){
      float v = sacc[k*64 + b];
      if constexpr (SQ==0) v *= (1.0f/32.0f);
      sq += v*v;
    }
    const float scale = sq/(1.f+sq)/sqrtf(sq+1e-7f);
    if constexpr (SQ==0){
      #pragma unroll
      for (int k=0;k<K_;++k)
        o_t[((size_t)j*K_ + k)*64 + b] = scale * sacc[k*64+b] * (1.0f/32.0f);
    } else if constexpr (SQ==1){
      #pragma unroll
      for (int k=0;k<K_;++k)
        o_t[((size_t)j*K_ + k)*64 + b] += scale * sacc[k*64+b];
    } else {
      const bool f32o = (flags[0]!=0) && (flags[1]!=0);
      if (f32o){
        float* po = (float*)d_out;
        #pragma unroll
        for (int k=0;k<K_;++k)
          po[(size_t)b*(J_*K_) + j*K_ + k] = scale * sacc[k*64+b];
      } else {
        __hip_bfloat16* po = (__hip_bfloat16*)d_out;
        #pragma unroll
        for (int k=0;k<K_;++k)
          po[(size_t)b*(J_*K_) + j*K_ + k] = __float2bfloat16(scale * sacc[k*64+b]);
      }
    }
  }
}

// ---- logits: LDS-free via operand swap; writes exp(logit) ---------------
// c_buf[n][j][b] = exp( sum_k o[b,j,k]*u_hat[b,j,n,k] )  (bounded, no max)
__global__ __launch_bounds__(256) void logits_kernel(
    const u16* __restrict__ X_p, const u16* __restrict__ W_p,
    const float* __restrict__ o_t, float* __restrict__ c_buf)
{
  const int l  = threadIdx.x & 63;
  const int w  = threadIdx.x >> 6;
  const int j  = blockIdx.y;
  const int n0 = blockIdx.x*32 + w*8;
  const int kc = l & 31;          // = column index = b (mod 32)
  const int h  = l >> 5;
  const int ih = h*8;

  float o_r0[16], o_r1[16];
  #pragma unroll
  for (int r=0;r<16;++r){
    const int k = (r&3) + 8*(r>>2) + 4*h;
    o_r0[r] = o_t[((size_t)j*K_ + k)*64 + kc];
    o_r1[r] = o_t[((size_t)j*K_ + k)*64 + 32 + kc];
  }

  #pragma unroll 2
  for (int t=0;t<8;++t){
    const int n = n0 + t;
    const u16* xp = X_p + (size_t)n*1024 + l*16;
    short8 xa0 = *(const short8*)xp;
    short8 xa1 = *(const short8*)(xp+8);
    short8 wfr = *(const short8*)(W_p + ((size_t)j*N_ + n)*512 + kc*16 + ih);
    f32x16 C0, C1;
    #pragma unroll
    for (int r=0;r<16;++r){ C0[r]=0.f; C1[r]=0.f; }
    C0 = __builtin_amdgcn_mfma_f32_32x32x16_bf16(wfr, xa0, C0, 0,0,0);
    C1 = __builtin_amdgcn_mfma_f32_32x32x16_bf16(wfr, xa1, C1, 0,0,0);
    float d0 = 0.f, d1 = 0.f;
    #pragma unroll
    for (int r=0;r<16;++r){ d0 += C0[r]*o_r0[r]; d1 += C1[r]*o_r1[r]; }
    d0 += __shfl_xor(d0, 32, 64);   // merge the two k-halves (same b)
    d1 += __shfl_xor(d1, 32, 64);
    const float val = (l >= 32) ? d1 : d0;   // lane l owns b=l
    c_buf[((size_t)n*J_ + j)*64 + l] = __expf(val);
  }
}

// ---- rowsum over j -> invS[n][b] (replaces normalize pass) --------------
__global__ __launch_bounds__(256) void rowsum(const float* __restrict__ c_buf,
                                              float* __restrict__ sumb)
{
  const int l = threadIdx.x & 63, w = threadIdx.x >> 6;
  const int n = blockIdx.x*4 + w;
  const float* p = c_buf + (size_t)n*J_*64 + l;
  float s = 0.f;
  #pragma unroll
  for (int jj=0;jj<J_;++jj) s += p[jj*64];
  sumb[(size_t)n*64 + l] = 1.0f/s;
}

extern "C" void kernel_launch(void* const* d_in, const int* in_sizes, int n_in,
                              void* d_out, int out_size, void* d_ws, size_t ws_size,
                              hipStream_t stream)
{
  const void* X  = d_in[0];   // [B][N][I]     (dtype sniffed)
  const void* Wm = d_in[1];   // [J][N][K][I]  (dtype sniffed)

  float* ws    = (float*)d_ws;
  float* o_t   = ws;                                  // 65536 f32, [j][k][b]
  int*   flags = (int*)(ws + 65536);                  // 2 ints (+pad)
  u16*   X_p   = (u16*)(ws + 65536 + 128);            // 2048*1024 u16 (4 MiB)
  u16*   W_p   = X_p + (size_t)N_*1024;               // 33.5M u16 (64 MiB)
  float* c_buf = (float*)(W_p + WTOT);                // 2048*32*64 f32 (16 MiB)
  float* sumb  = c_buf + (size_t)N_*J_*64;            // 2048*64 f32 (512 KiB)
  float* part  = sumb + (size_t)N_*64;                // CH_*32*2048 f32 (8 MiB)
  // total ~93 MiB of the 512 MiB workspace

  const dim3 blk(256);
  const dim3 g_ac(CH_, J_);    // accum: 1024 blocks
  const dim3 g_lg(64,  J_);    // logits: 2048 blocks

  detect<<<1, blk, 0, stream>>>((const u16*)X, (const u16*)Wm, flags);
  pack_xw<<<8192 + N_/4, blk, 0, stream>>>(X, Wm, flags, X_p, W_p);

  // iter 0: uniform c (1/32 folded into squash epilogue)
  accum_kernel<0><<<g_ac, blk, 0, stream>>>(X_p, W_p, nullptr, nullptr, part);
  reduce_squash<0><<<J_, blk, 0, stream>>>(part, o_t, flags, nullptr);

  // iter 1
  logits_kernel<<<g_lg, blk, 0, stream>>>(X_p, W_p, o_t, c_buf);
  rowsum<<<N_/4, blk, 0, stream>>>(c_buf, sumb);
  accum_kernel<1><<<g_ac, blk, 0, stream>>>(X_p, W_p, c_buf, sumb, part);
  reduce_squash<1><<<J_, blk, 0, stream>>>(part, o_t, flags, nullptr);

  // iter 2
  logits_kernel<<<g_lg, blk, 0, stream>>>(X_p, W_p, o_t, c_buf);
  rowsum<<<N_/4, blk, 0, stream>>>(c_buf, sumb);
  accum_kernel<1><<<g_ac, blk, 0, stream>>>(X_p, W_p, c_buf, sumb, part);
  reduce_squash<2><<<J_, blk, 0, stream>>>(part, o_t, flags, d_out);
}

// Round 4
// 323.332 us; speedup vs baseline: 2.0777x; 1.1793x over previous
//
#include <hip/hip_runtime.h>
#include <hip/hip_bf16.h>

typedef unsigned int  u32;
typedef unsigned short u16;
typedef __attribute__((ext_vector_type(8)))  short short8;
typedef __attribute__((ext_vector_type(16))) float f32x16;

#define B_ 64
#define N_ 2048
#define I_ 16
#define J_ 32
#define K_ 32
#define CH_  32        // n-chunks for accum (block covers 64 n, wave 16)
#define WTOT ((size_t)J_*N_*K_*I_)   // 33,554,432 W elements

__device__ __forceinline__ float bf2f(u16 u){ return __uint_as_float(((u32)u)<<16); }
__device__ __forceinline__ short f2bf(float f){
  __hip_bfloat16 h = __float2bfloat16(f);
  short s; __builtin_memcpy(&s, &h, 2); return s;
}

// ---- dtype sniffer (1 block) — in_sizes is element count, can't use it --
__global__ __launch_bounds__(256) void detect(const u16* __restrict__ X,
                                              const u16* __restrict__ W,
                                              int* __restrict__ flags)
{
  __shared__ int sx, sw;
  if (threadIdx.x == 0){ sx = 0; sw = 0; }
  __syncthreads();
  int bx = 0, bw = 0;
  for (int i = threadIdx.x; i < 8192; i += 256){
    int ex = (X[2*i] >> 7) & 0xFF;
    int ew = (W[2*i] >> 7) & 0xFF;
    if (ex >= 0x90) bx = 1;
    if (ew >= 0x90) bw = 1;
  }
  if (bx) atomicOr(&sx, 1);
  if (bw) atomicOr(&sw, 1);
  __syncthreads();
  if (threadIdx.x == 0){ flags[0] = sx; flags[1] = sw; }
}

// ---- merged pack: blocks [0,8192) pack W, [8192,8704) pack X ------------
// X_p[n][lane][t*8+q] = bf16( x[b = t*32+(lane&31)][n][i = (lane>>5)*8+q] )
__global__ __launch_bounds__(256) void pack_xw(const void* __restrict__ Xv,
                                               const void* __restrict__ Wv,
                                               const int* __restrict__ flags,
                                               u16* __restrict__ X_p,
                                               u16* __restrict__ W_p)
{
  if (blockIdx.x < 8192){
    const size_t base = ((size_t)blockIdx.x*256 + threadIdx.x)*16;
    if (flags[1]){
      const float4* src = (const float4*)((const float*)Wv + base);
      float4 v0=src[0], v1=src[1], v2=src[2], v3=src[3];
      short8 a, b;
      a[0]=f2bf(v0.x); a[1]=f2bf(v0.y); a[2]=f2bf(v0.z); a[3]=f2bf(v0.w);
      a[4]=f2bf(v1.x); a[5]=f2bf(v1.y); a[6]=f2bf(v1.z); a[7]=f2bf(v1.w);
      b[0]=f2bf(v2.x); b[1]=f2bf(v2.y); b[2]=f2bf(v2.z); b[3]=f2bf(v2.w);
      b[4]=f2bf(v3.x); b[5]=f2bf(v3.y); b[6]=f2bf(v3.z); b[7]=f2bf(v3.w);
      *(short8*)(W_p + base)     = a;
      *(short8*)(W_p + base + 8) = b;
    } else {
      const short8* src = (const short8*)((const u16*)Wv + base);
      *(short8*)(W_p + base)     = src[0];
      *(short8*)(W_p + base + 8) = src[1];
    }
  } else {
    const int bid = blockIdx.x - 8192;
    const int l = threadIdx.x & 63, w = threadIdx.x >> 6;
    const int n = bid*4 + w;
    const bool xf32 = flags[0] != 0;
    const int ih = (l>>5)*8;
    u16 out[16];
    #pragma unroll
    for (int t=0;t<2;++t){
      const int b = t*32 + (l&31);
      if (xf32){
        const float4* xp = (const float4*)((const float*)Xv + ((size_t)b*N_ + n)*I_ + ih);
        float4 v0 = xp[0], v1 = xp[1];
        out[t*8+0]=(u16)f2bf(v0.x); out[t*8+1]=(u16)f2bf(v0.y);
        out[t*8+2]=(u16)f2bf(v0.z); out[t*8+3]=(u16)f2bf(v0.w);
        out[t*8+4]=(u16)f2bf(v1.x); out[t*8+5]=(u16)f2bf(v1.y);
        out[t*8+6]=(u16)f2bf(v1.z); out[t*8+7]=(u16)f2bf(v1.w);
      } else {
        const u16* xp = (const u16*)Xv + ((size_t)b*N_ + n)*I_ + ih;
        #pragma unroll
        for (int q=0;q<8;++q) out[t*8+q] = xp[q];
      }
    }
    u16* dst = X_p + (size_t)n*1024 + l*16;
    short8 s0, s1;
    #pragma unroll
    for (int q=0;q<8;++q){ s0[q]=(short)out[q]; s1[q]=(short)out[8+q]; }
    *(short8*)dst = s0;
    *(short8*)(dst+8) = s1;
  }
}

// ---- accum: per-(chunk,j) partial of s via MFMA (A=X, B=W), no atomics --
// R: 0 = uniform c (1/32 folded in squash), 1 = weighted c = e * invS
template<int R>
__global__ __launch_bounds__(256) void accum_kernel(
    const u16* __restrict__ X_p, const u16* __restrict__ W_p,
    const float* __restrict__ c_buf, const float* __restrict__ sumb,
    float* __restrict__ part)
{
  __shared__ float red[4][2048];
  const int l  = threadIdx.x & 63;
  const int w  = threadIdx.x >> 6;
  const int j  = blockIdx.y;
  const int ch = blockIdx.x;
  const int n0 = ch*64 + w*16;
  const int kc = l & 31;
  const int ih = (l >> 5) * 8;

  f32x16 C0, C1;
  #pragma unroll
  for (int r=0;r<16;++r){ C0[r]=0.f; C1[r]=0.f; }

  #pragma unroll 4
  for (int t=0;t<16;++t){
    const int n = n0 + t;
    const u16* xp = X_p + (size_t)n*1024 + l*16;
    short8 xa0 = *(const short8*)xp;
    short8 xa1 = *(const short8*)(xp+8);
    short8 a0, a1;
    if constexpr (R==0){ a0 = xa0; a1 = xa1; }
    else {
      const float iS0 = sumb[(size_t)n*64 + kc];
      const float iS1 = sumb[(size_t)n*64 + 32 + kc];
      const float c0 = iS0 * c_buf[((size_t)n*J_ + j)*64 + kc];
      const float c1 = iS1 * c_buf[((size_t)n*J_ + j)*64 + 32 + kc];
      #pragma unroll
      for (int q=0;q<8;++q){
        a0[q] = f2bf(c0 * bf2f((u16)xa0[q]));
        a1[q] = f2bf(c1 * bf2f((u16)xa1[q]));
      }
    }
    short8 bfr = *(const short8*)(W_p + ((size_t)j*N_ + n)*512 + kc*16 + ih);
    C0 = __builtin_amdgcn_mfma_f32_32x32x16_bf16(a0, bfr, C0, 0,0,0);
    C1 = __builtin_amdgcn_mfma_f32_32x32x16_bf16(a1, bfr, C1, 0,0,0);
  }

  #pragma unroll
  for (int r=0;r<16;++r){
    red[w][r*64 + l]      = C0[r];
    red[w][(16+r)*64 + l] = C1[r];
  }
  __syncthreads();

  float* dst = part + ((size_t)ch*J_ + j)*2048;
  #pragma unroll
  for (int p = threadIdx.x; p < 2048; p += 256)
    dst[p] = red[0][p] + red[1][p] + red[2][p] + red[3][p];
}

// ---- reduce partials + squash, PARALLEL: 256 blocks = (j x 8 r-segments)
// For fixed output b, all 32 k live in one 64-float row r of part:
//   each (r,l) = one (k=l&31, b(tile,rr,h)); 5-step shfl_xor butterfly
//   within each 32-lane half sums v^2 over the 32 k's of that b.
// SQ: 0 = write o_t (iter0, c=1/32), 1 = o_t += (iter1), 2 = write d_out
template<int SQ>
__global__ __launch_bounds__(256) void reduce_squash(
    const float* __restrict__ part, float* __restrict__ o_t,
    const int* __restrict__ flags, void* __restrict__ d_out)
{
  const int j    = blockIdx.x & 31;
  const int rseg = blockIdx.x >> 5;        // 0..7
  const int rl   = threadIdx.x >> 6;       // 0..3
  const int l    = threadIdx.x & 63;
  const int r    = rseg*4 + rl;            // 0..31
  const int p    = r*64 + l;

  float sum = 0.f;
  const float* src = part + (size_t)j*2048 + p;
  #pragma unroll 8
  for (int ch=0; ch<CH_; ++ch)
    sum += src[(size_t)ch*J_*2048];

  const int kc = l & 31, h = l >> 5;
  const int rr = r & 15, tile = r >> 4;
  const int b  = tile*32 + (rr&3) + 8*(rr>>2) + 4*h;

  float v = sum;
  if constexpr (SQ==0) v *= (1.0f/32.0f);

  float sq = v*v;                          // sum over the 32 k's sharing b
  sq += __shfl_xor(sq, 1,  64);
  sq += __shfl_xor(sq, 2,  64);
  sq += __shfl_xor(sq, 4,  64);
  sq += __shfl_xor(sq, 8,  64);
  sq += __shfl_xor(sq, 16, 64);
  const float scale = sq/(1.f+sq)/sqrtf(sq+1e-7f);

  if constexpr (SQ==0){
    o_t[((size_t)j*K_ + kc)*64 + b] = scale * v;
  } else if constexpr (SQ==1){
    o_t[((size_t)j*K_ + kc)*64 + b] += scale * v;
  } else {
    const bool f32o = (flags[0]!=0) && (flags[1]!=0);
    if (f32o){
      ((float*)d_out)[(size_t)b*(J_*K_) + j*K_ + kc] = scale * v;
    } else {
      ((__hip_bfloat16*)d_out)[(size_t)b*(J_*K_) + j*K_ + kc] = __float2bfloat16(scale * v);
    }
  }
}

// ---- logits: LDS-free via operand swap; writes exp(logit) ---------------
// c_buf[n][j][b] = exp( sum_k o[b,j,k]*u_hat[b,j,n,k] )  (bounded, no max)
__global__ __launch_bounds__(256) void logits_kernel(
    const u16* __restrict__ X_p, const u16* __restrict__ W_p,
    const float* __restrict__ o_t, float* __restrict__ c_buf)
{
  const int l  = threadIdx.x & 63;
  const int w  = threadIdx.x >> 6;
  const int j  = blockIdx.y;
  const int n0 = blockIdx.x*32 + w*8;
  const int kc = l & 31;          // = column index = b (mod 32)
  const int h  = l >> 5;
  const int ih = h*8;

  float o_r0[16], o_r1[16];
  #pragma unroll
  for (int r=0;r<16;++r){
    const int k = (r&3) + 8*(r>>2) + 4*h;
    o_r0[r] = o_t[((size_t)j*K_ + k)*64 + kc];
    o_r1[r] = o_t[((size_t)j*K_ + k)*64 + 32 + kc];
  }

  #pragma unroll 2
  for (int t=0;t<8;++t){
    const int n = n0 + t;
    const u16* xp = X_p + (size_t)n*1024 + l*16;
    short8 xa0 = *(const short8*)xp;
    short8 xa1 = *(const short8*)(xp+8);
    short8 wfr = *(const short8*)(W_p + ((size_t)j*N_ + n)*512 + kc*16 + ih);
    f32x16 C0, C1;
    #pragma unroll
    for (int r=0;r<16;++r){ C0[r]=0.f; C1[r]=0.f; }
    C0 = __builtin_amdgcn_mfma_f32_32x32x16_bf16(wfr, xa0, C0, 0,0,0);
    C1 = __builtin_amdgcn_mfma_f32_32x32x16_bf16(wfr, xa1, C1, 0,0,0);
    float d0 = 0.f, d1 = 0.f;
    #pragma unroll
    for (int r=0;r<16;++r){ d0 += C0[r]*o_r0[r]; d1 += C1[r]*o_r1[r]; }
    d0 += __shfl_xor(d0, 32, 64);   // merge the two k-halves (same b)
    d1 += __shfl_xor(d1, 32, 64);
    const float val = (l >= 32) ? d1 : d0;   // lane l owns b=l
    c_buf[((size_t)n*J_ + j)*64 + l] = __expf(val);
  }
}

// ---- rowsum over j -> invS[n][b] (replaces normalize pass) --------------
__global__ __launch_bounds__(256) void rowsum(const float* __restrict__ c_buf,
                                              float* __restrict__ sumb)
{
  const int l = threadIdx.x & 63, w = threadIdx.x >> 6;
  const int n = blockIdx.x*4 + w;
  const float* p = c_buf + (size_t)n*J_*64 + l;
  float s = 0.f;
  #pragma unroll
  for (int jj=0;jj<J_;++jj) s += p[jj*64];
  sumb[(size_t)n*64 + l] = 1.0f/s;
}

extern "C" void kernel_launch(void* const* d_in, const int* in_sizes, int n_in,
                              void* d_out, int out_size, void* d_ws, size_t ws_size,
                              hipStream_t stream)
{
  const void* X  = d_in[0];   // [B][N][I]     (dtype sniffed on device)
  const void* Wm = d_in[1];   // [J][N][K][I]  (dtype sniffed on device)

  float* ws    = (float*)d_ws;
  float* o_t   = ws;                                  // 65536 f32, [j][k][b]
  int*   flags = (int*)(ws + 65536);                  // 2 ints (+pad)
  u16*   X_p   = (u16*)(ws + 65536 + 128);            // 2048*1024 u16 (4 MiB)
  u16*   W_p   = X_p + (size_t)N_*1024;               // 33.5M u16 (64 MiB)
  float* c_buf = (float*)(W_p + WTOT);                // 2048*32*64 f32 (16 MiB)
  float* sumb  = c_buf + (size_t)N_*J_*64;            // 2048*64 f32 (512 KiB)
  float* part  = sumb + (size_t)N_*64;                // CH_*32*2048 f32 (8 MiB)
  // total ~93 MiB of the 512 MiB workspace

  const dim3 blk(256);
  const dim3 g_ac(CH_, J_);    // accum: 1024 blocks
  const dim3 g_lg(64,  J_);    // logits: 2048 blocks

  detect<<<1, blk, 0, stream>>>((const u16*)X, (const u16*)Wm, flags);
  pack_xw<<<8192 + N_/4, blk, 0, stream>>>(X, Wm, flags, X_p, W_p);

  // iter 0: uniform c (1/32 folded into squash epilogue)
  accum_kernel<0><<<g_ac, blk, 0, stream>>>(X_p, W_p, nullptr, nullptr, part);
  reduce_squash<0><<<256, blk, 0, stream>>>(part, o_t, flags, nullptr);

  // iter 1
  logits_kernel<<<g_lg, blk, 0, stream>>>(X_p, W_p, o_t, c_buf);
  rowsum<<<N_/4, blk, 0, stream>>>(c_buf, sumb);
  accum_kernel<1><<<g_ac, blk, 0, stream>>>(X_p, W_p, c_buf, sumb, part);
  reduce_squash<1><<<256, blk, 0, stream>>>(part, o_t, flags, nullptr);

  // iter 2
  logits_kernel<<<g_lg, blk, 0, stream>>>(X_p, W_p, o_t, c_buf);
  rowsum<<<N_/4, blk, 0, stream>>>(c_buf, sumb);
  accum_kernel<1><<<g_ac, blk, 0, stream>>>(X_p, W_p, c_buf, sumb, part);
  reduce_squash<2><<<256, blk, 0, stream>>>(part, o_t, flags, d_out);
}

// Round 6
// 305.296 us; speedup vs baseline: 2.2004x; 1.0591x over previous
//
#include <hip/hip_runtime.h>
#include <hip/hip_bf16.h>

typedef unsigned int  u32;
typedef unsigned short u16;
typedef __attribute__((ext_vector_type(8)))  short short8;
typedef __attribute__((ext_vector_type(16))) float f32x16;

#define B_ 64
#define N_ 2048
#define I_ 16
#define J_ 32
#define K_ 32
#define CH_  32        // n-chunks for accum (block covers 64 n, wave 16)
#define WTOT ((size_t)J_*N_*K_*I_)   // 33,554,432 W elements

__device__ __forceinline__ float bf2f(u16 u){ return __uint_as_float(((u32)u)<<16); }
__device__ __forceinline__ short f2bf(float f){
  __hip_bfloat16 h = __float2bfloat16(f);
  short s; __builtin_memcpy(&s, &h, 2); return s;
}

// Per-block dtype self-sniff: 256 samples of the low u16s of the first
// 512 bytes. f32 low-halves have ~uniform bits -> exponent-field test
// fires w.p. 0.4375/sample (P(miss all) ~ 1e-32); bf16 N(0,1) never fires.
__device__ __forceinline__ bool sniff_f32(const u16* p, int* sh)
{
  if (threadIdx.x == 0) *sh = 0;
  __syncthreads();
  int hit = ((p[2*threadIdx.x] >> 7) & 0xFF) >= 0x90;
  if (__any(hit) && (threadIdx.x & 63) == 0) atomicOr(sh, 1);
  __syncthreads();
  return *sh != 0;
}

// ---- pack X (512 blocks); block 0 also publishes flags for epilogue -----
// X_p[n][lane][t*8+q] = bf16( x[b = t*32+(lane&31)][n][i = (lane>>5)*8+q] )
__global__ __launch_bounds__(256) void pack_x_det(const void* __restrict__ Xv,
                                                  const void* __restrict__ Wv,
                                                  int* __restrict__ flags,
                                                  u16* __restrict__ X_p)
{
  __shared__ int sx, sw;
  const bool xf32 = sniff_f32((const u16*)Xv, &sx);
  if (blockIdx.x == 0){
    const bool wf32 = sniff_f32((const u16*)Wv, &sw);
    if (threadIdx.x == 0){ flags[0] = xf32 ? 1 : 0; flags[1] = wf32 ? 1 : 0; }
  }

  const int l = threadIdx.x & 63, w = threadIdx.x >> 6;
  const int n = blockIdx.x*4 + w;
  const int ih = (l>>5)*8;
  u16 out[16];
  #pragma unroll
  for (int t=0;t<2;++t){
    const int b = t*32 + (l&31);
    if (xf32){
      const float4* xp = (const float4*)((const float*)Xv + ((size_t)b*N_ + n)*I_ + ih);
      float4 v0 = xp[0], v1 = xp[1];
      out[t*8+0]=(u16)f2bf(v0.x); out[t*8+1]=(u16)f2bf(v0.y);
      out[t*8+2]=(u16)f2bf(v0.z); out[t*8+3]=(u16)f2bf(v0.w);
      out[t*8+4]=(u16)f2bf(v1.x); out[t*8+5]=(u16)f2bf(v1.y);
      out[t*8+6]=(u16)f2bf(v1.z); out[t*8+7]=(u16)f2bf(v1.w);
    } else {
      const u16* xp = (const u16*)Xv + ((size_t)b*N_ + n)*I_ + ih;
      #pragma unroll
      for (int q=0;q<8;++q) out[t*8+q] = xp[q];
    }
  }
  u16* dst = X_p + (size_t)n*1024 + l*16;
  short8 s0, s1;
  #pragma unroll
  for (int q=0;q<8;++q){ s0[q]=(short)out[q]; s1[q]=(short)out[8+q]; }
  *(short8*)dst = s0;
  *(short8*)(dst+8) = s1;
}

// ---- iter-0 accum FUSED with W pack: read W raw, cvt, MFMA, store bf16 --
// Each (j,n) fragment is touched by exactly one (ch,j) block -> each lane
// converts and stores exactly the 8 elements it consumes.
__global__ __launch_bounds__(256) void accum0_packw(
    const u16* __restrict__ X_p, const void* __restrict__ Wv,
    u16* __restrict__ W_p, float* __restrict__ part)
{
  __shared__ float red[4][2048];
  __shared__ int swf;
  const bool wf32 = sniff_f32((const u16*)Wv, &swf);

  const int l  = threadIdx.x & 63;
  const int w  = threadIdx.x >> 6;
  const int j  = blockIdx.y;
  const int ch = blockIdx.x;
  const int n0 = ch*64 + w*16;
  const int kc = l & 31;
  const int ih = (l >> 5) * 8;

  f32x16 C0, C1;
  #pragma unroll
  for (int r=0;r<16;++r){ C0[r]=0.f; C1[r]=0.f; }

  #pragma unroll 4
  for (int t=0;t<16;++t){
    const int n = n0 + t;
    const u16* xp = X_p + (size_t)n*1024 + l*16;
    short8 xa0 = *(const short8*)xp;
    short8 xa1 = *(const short8*)(xp+8);

    const size_t wbase = ((size_t)j*N_ + n)*512 + kc*16 + ih;
    short8 bfr;
    if (wf32){
      const float4* wp = (const float4*)((const float*)Wv + wbase);
      float4 u0 = wp[0], u1 = wp[1];
      bfr[0]=f2bf(u0.x); bfr[1]=f2bf(u0.y); bfr[2]=f2bf(u0.z); bfr[3]=f2bf(u0.w);
      bfr[4]=f2bf(u1.x); bfr[5]=f2bf(u1.y); bfr[6]=f2bf(u1.z); bfr[7]=f2bf(u1.w);
    } else {
      bfr = *(const short8*)((const u16*)Wv + wbase);
    }
    *(short8*)(W_p + wbase) = bfr;

    C0 = __builtin_amdgcn_mfma_f32_32x32x16_bf16(xa0, bfr, C0, 0,0,0);
    C1 = __builtin_amdgcn_mfma_f32_32x32x16_bf16(xa1, bfr, C1, 0,0,0);
  }

  #pragma unroll
  for (int r=0;r<16;++r){
    red[w][r*64 + l]      = C0[r];
    red[w][(16+r)*64 + l] = C1[r];
  }
  __syncthreads();

  float* dst = part + ((size_t)ch*J_ + j)*2048;
  #pragma unroll
  for (int p = threadIdx.x; p < 2048; p += 256)
    dst[p] = red[0][p] + red[1][p] + red[2][p] + red[3][p];
}

// ---- accum (weighted c = e * invS), reads packed W_p --------------------
__global__ __launch_bounds__(256) void accum1_kernel(
    const u16* __restrict__ X_p, const u16* __restrict__ W_p,
    const float* __restrict__ c_buf, const float* __restrict__ sumb,
    float* __restrict__ part)
{
  __shared__ float red[4][2048];
  const int l  = threadIdx.x & 63;
  const int w  = threadIdx.x >> 6;
  const int j  = blockIdx.y;
  const int ch = blockIdx.x;
  const int n0 = ch*64 + w*16;
  const int kc = l & 31;
  const int ih = (l >> 5) * 8;

  f32x16 C0, C1;
  #pragma unroll
  for (int r=0;r<16;++r){ C0[r]=0.f; C1[r]=0.f; }

  #pragma unroll 4
  for (int t=0;t<16;++t){
    const int n = n0 + t;
    const u16* xp = X_p + (size_t)n*1024 + l*16;
    short8 xa0 = *(const short8*)xp;
    short8 xa1 = *(const short8*)(xp+8);
    const float iS0 = sumb[(size_t)n*64 + kc];
    const float iS1 = sumb[(size_t)n*64 + 32 + kc];
    const float c0 = iS0 * c_buf[((size_t)n*J_ + j)*64 + kc];
    const float c1 = iS1 * c_buf[((size_t)n*J_ + j)*64 + 32 + kc];
    short8 a0, a1;
    #pragma unroll
    for (int q=0;q<8;++q){
      a0[q] = f2bf(c0 * bf2f((u16)xa0[q]));
      a1[q] = f2bf(c1 * bf2f((u16)xa1[q]));
    }
    short8 bfr = *(const short8*)(W_p + ((size_t)j*N_ + n)*512 + kc*16 + ih);
    C0 = __builtin_amdgcn_mfma_f32_32x32x16_bf16(a0, bfr, C0, 0,0,0);
    C1 = __builtin_amdgcn_mfma_f32_32x32x16_bf16(a1, bfr, C1, 0,0,0);
  }

  #pragma unroll
  for (int r=0;r<16;++r){
    red[w][r*64 + l]      = C0[r];
    red[w][(16+r)*64 + l] = C1[r];
  }
  __syncthreads();

  float* dst = part + ((size_t)ch*J_ + j)*2048;
  #pragma unroll
  for (int p = threadIdx.x; p < 2048; p += 256)
    dst[p] = red[0][p] + red[1][p] + red[2][p] + red[3][p];
}

// ---- reduce partials + squash, PARALLEL: 256 blocks = (j x 8 r-segments)
// SQ: 0 = write o_t (iter0, c=1/32), 1 = o_t += (iter1), 2 = write d_out
template<int SQ>
__global__ __launch_bounds__(256) void reduce_squash(
    const float* __restrict__ part, float* __restrict__ o_t,
    const int* __restrict__ flags, void* __restrict__ d_out)
{
  const int j    = blockIdx.x & 31;
  const int rseg = blockIdx.x >> 5;        // 0..7
  const int rl   = threadIdx.x >> 6;       // 0..3
  const int l    = threadIdx.x & 63;
  const int r    = rseg*4 + rl;            // 0..31
  const int p    = r*64 + l;

  float sum = 0.f;
  const float* src = part + (size_t)j*2048 + p;
  #pragma unroll 8
  for (int ch=0; ch<CH_; ++ch)
    sum += src[(size_t)ch*J_*2048];

  const int kc = l & 31, h = l >> 5;
  const int rr = r & 15, tile = r >> 4;
  const int b  = tile*32 + (rr&3) + 8*(rr>>2) + 4*h;

  float v = sum;
  if constexpr (SQ==0) v *= (1.0f/32.0f);

  float sq = v*v;                          // sum over the 32 k's sharing b
  sq += __shfl_xor(sq, 1,  64);
  sq += __shfl_xor(sq, 2,  64);
  sq += __shfl_xor(sq, 4,  64);
  sq += __shfl_xor(sq, 8,  64);
  sq += __shfl_xor(sq, 16, 64);
  const float scale = sq/(1.f+sq)/sqrtf(sq+1e-7f);

  if constexpr (SQ==0){
    o_t[((size_t)j*K_ + kc)*64 + b] = scale * v;
  } else if constexpr (SQ==1){
    o_t[((size_t)j*K_ + kc)*64 + b] += scale * v;
  } else {
    const bool f32o = (flags[0]!=0) && (flags[1]!=0);
    if (f32o){
      ((float*)d_out)[(size_t)b*(J_*K_) + j*K_ + kc] = scale * v;
    } else {
      ((__hip_bfloat16*)d_out)[(size_t)b*(J_*K_) + j*K_ + kc] = __float2bfloat16(scale * v);
    }
  }
}

// ---- logits: LDS-free via operand swap; writes exp(logit) ---------------
// c_buf[n][j][b] = exp( sum_k o[b,j,k]*u_hat[b,j,n,k] )  (bounded, no max)
__global__ __launch_bounds__(256) void logits_kernel(
    const u16* __restrict__ X_p, const u16* __restrict__ W_p,
    const float* __restrict__ o_t, float* __restrict__ c_buf)
{
  const int l  = threadIdx.x & 63;
  const int w  = threadIdx.x >> 6;
  const int j  = blockIdx.y;
  const int n0 = blockIdx.x*32 + w*8;
  const int kc = l & 31;          // = column index = b (mod 32)
  const int h  = l >> 5;
  const int ih = h*8;

  float o_r0[16], o_r1[16];
  #pragma unroll
  for (int r=0;r<16;++r){
    const int k = (r&3) + 8*(r>>2) + 4*h;
    o_r0[r] = o_t[((size_t)j*K_ + k)*64 + kc];
    o_r1[r] = o_t[((size_t)j*K_ + k)*64 + 32 + kc];
  }

  #pragma unroll 2
  for (int t=0;t<8;++t){
    const int n = n0 + t;
    const u16* xp = X_p + (size_t)n*1024 + l*16;
    short8 xa0 = *(const short8*)xp;
    short8 xa1 = *(const short8*)(xp+8);
    short8 wfr = *(const short8*)(W_p + ((size_t)j*N_ + n)*512 + kc*16 + ih);
    f32x16 C0, C1;
    #pragma unroll
    for (int r=0;r<16;++r){ C0[r]=0.f; C1[r]=0.f; }
    C0 = __builtin_amdgcn_mfma_f32_32x32x16_bf16(wfr, xa0, C0, 0,0,0);
    C1 = __builtin_amdgcn_mfma_f32_32x32x16_bf16(wfr, xa1, C1, 0,0,0);
    float d0 = 0.f, d1 = 0.f;
    #pragma unroll
    for (int r=0;r<16;++r){ d0 += C0[r]*o_r0[r]; d1 += C1[r]*o_r1[r]; }
    d0 += __shfl_xor(d0, 32, 64);   // merge the two k-halves (same b)
    d1 += __shfl_xor(d1, 32, 64);
    const float val = (l >= 32) ? d1 : d0;   // lane l owns b=l
    c_buf[((size_t)n*J_ + j)*64 + l] = __expf(val);
  }
}

// ---- rowsum over j -> invS[n][b] (replaces normalize pass) --------------
__global__ __launch_bounds__(256) void rowsum(const float* __restrict__ c_buf,
                                              float* __restrict__ sumb)
{
  const int l = threadIdx.x & 63, w = threadIdx.x >> 6;
  const int n = blockIdx.x*4 + w;
  const float* p = c_buf + (size_t)n*J_*64 + l;
  float s = 0.f;
  #pragma unroll
  for (int jj=0;jj<J_;++jj) s += p[jj*64];
  sumb[(size_t)n*64 + l] = 1.0f/s;
}

extern "C" void kernel_launch(void* const* d_in, const int* in_sizes, int n_in,
                              void* d_out, int out_size, void* d_ws, size_t ws_size,
                              hipStream_t stream)
{
  const void* X  = d_in[0];   // [B][N][I]     (dtype self-sniffed per block)
  const void* Wm = d_in[1];   // [J][N][K][I]  (dtype self-sniffed per block)

  float* ws    = (float*)d_ws;
  float* o_t   = ws;                                  // 65536 f32, [j][k][b]
  int*   flags = (int*)(ws + 65536);                  // 2 ints (+pad)
  u16*   X_p   = (u16*)(ws + 65536 + 128);            // 2048*1024 u16 (4 MiB)
  u16*   W_p   = X_p + (size_t)N_*1024;               // 33.5M u16 (64 MiB)
  float* c_buf = (float*)(W_p + WTOT);                // 2048*32*64 f32 (16 MiB)
  float* sumb  = c_buf + (size_t)N_*J_*64;            // 2048*64 f32 (512 KiB)
  float* part  = sumb + (size_t)N_*64;                // CH_*32*2048 f32 (8 MiB)
  // total ~93 MiB of the 512 MiB workspace

  const dim3 blk(256);
  const dim3 g_ac(CH_, J_);    // accum: 1024 blocks
  const dim3 g_lg(64,  J_);    // logits: 2048 blocks

  pack_x_det<<<N_/4, blk, 0, stream>>>(X, Wm, flags, X_p);

  // iter 0: uniform c (1/32 folded into squash); W pack fused into accum
  accum0_packw<<<g_ac, blk, 0, stream>>>(X_p, Wm, W_p, part);
  reduce_squash<0><<<256, blk, 0, stream>>>(part, o_t, flags, nullptr);

  // iter 1
  logits_kernel<<<g_lg, blk, 0, stream>>>(X_p, W_p, o_t, c_buf);
  rowsum<<<N_/4, blk, 0, stream>>>(c_buf, sumb);
  accum1_kernel<<<g_ac, blk, 0, stream>>>(X_p, W_p, c_buf, sumb, part);
  reduce_squash<1><<<256, blk, 0, stream>>>(part, o_t, flags, nullptr);

  // iter 2
  logits_kernel<<<g_lg, blk, 0, stream>>>(X_p, W_p, o_t, c_buf);
  rowsum<<<N_/4, blk, 0, stream>>>(c_buf, sumb);
  accum1_kernel<<<g_ac, blk, 0, stream>>>(X_p, W_p, c_buf, sumb, part);
  reduce_squash<2><<<256, blk, 0, stream>>>(part, o_t, flags, d_out);
}